// Round 4
// baseline (2071.961 us; speedup 1.0000x reference)
//
#include <hip/hip_runtime.h>
#include <cstdint>
#include <cstddef>

typedef unsigned int u32;
typedef unsigned short u16;

#define BB 16
#define CMEL 80
#define DRES 256
#define TXN 1024
#define TYN 4096
#define NEGV (-1e9f)

// output offsets (in floats), concatenated in reference return order
#define OFF_ZM    0ull
#define OFF_ZMASK 16777216ull
#define OFF_ATTN  16842752ull
#define OFF_LOGW  83951616ull
#define OFF_LOSS  83968000ull
#define OFF_MPROJ 83968001ull

// ws offsets (bytes)
#define WS_X2   0
#define WS_Z2   262144
#define WS_IDX  1310720
#define WS_PART 1572864

// global_load_lds: 16B per lane; LDS dst = lp + lane*16 (wave-uniform base),
// global src = per-lane gp. offset imm kept 0 ALWAYS: on GCN-lineage LDS-DMA the
// inst offset can be added to the LDS side too (R3 bug) — advance pointers instead.
#define GLLDS(gp, lp) \
  __builtin_amdgcn_global_load_lds((const __attribute__((address_space(1))) void*)(gp), \
                                   (__attribute__((address_space(3))) void*)(lp), 16, 0, 0)

// ---------------- K1: row norms + z_mask ----------------
__global__ __launch_bounds__(1024) void k1_prep(
    const float* __restrict__ xm, const float* __restrict__ mel,
    const int* __restrict__ mlen,
    float* __restrict__ x2n, float* __restrict__ z2n, float* __restrict__ out_zmask) {
  int b = blockIdx.x;
  int slice = blockIdx.y;
  int t = threadIdx.x;
  if (slice == 0) {
    float acc = 0.f;
    const float* p = xm + (size_t)b * CMEL * TXN + t;
    #pragma unroll 4
    for (int c = 0; c < CMEL; ++c) { float v = p[(size_t)c * TXN]; acc = fmaf(v, v, acc); }
    x2n[b * TXN + t] = -acc;
  } else {
    int j = (slice - 1) * 1024 + t;
    float acc = 0.f;
    const float* p = mel + (size_t)b * CMEL * TYN + j;
    #pragma unroll 4
    for (int c = 0; c < CMEL; ++c) { float v = p[(size_t)c * TYN]; acc = fmaf(v, v, acc); }
    z2n[b * TYN + j] = -acc;
    out_zmask[b * TYN + j] = (j < mlen[b]) ? 1.0f : 0.0f;
  }
}

// ---------------- K2: corr GEMM -> val_T[b][j][x] (masked) ----------------
// NOTE: accumulation structure frozen — bit-matches numpy reference (absmax 0.0).
__global__ __launch_bounds__(256) void k2_corr(
    const float* __restrict__ xm, const float* __restrict__ mel,
    const float* __restrict__ x2n, const float* __restrict__ z2n,
    const int* __restrict__ xlen, const int* __restrict__ mlen,
    float* __restrict__ valT) {
  int b = blockIdx.z;
  int ml = mlen[b];
  int j0 = blockIdx.y * 128;
  if (j0 >= ml) return;   // rows never read by DP
  int xl = xlen[b];
  int x0 = blockIdx.x * 128;

  __shared__ float sA[40][128];
  __shared__ float sB[40][128];

  int t = threadIdx.x;
  int i16 = t & 15, j16 = t >> 4;

  float acc[2][4][2][4];  // [p][jj][q][i]
  #pragma unroll
  for (int p = 0; p < 2; ++p)
    #pragma unroll
    for (int jj = 0; jj < 4; ++jj)
      #pragma unroll
      for (int q = 0; q < 2; ++q)
        #pragma unroll
        for (int i = 0; i < 4; ++i) acc[p][jj][q][i] = 0.f;

  for (int c0 = 0; c0 < CMEL; c0 += 40) {
    __syncthreads();
    for (int i = t; i < 40 * 32; i += 256) {
      int c = i >> 5, q = i & 31;
      *(float4*)&sA[c][q * 4] =
          *(const float4*)(xm + (size_t)(b * CMEL + c0 + c) * TXN + x0 + q * 4);
      *(float4*)&sB[c][q * 4] =
          *(const float4*)(mel + (size_t)(b * CMEL + c0 + c) * TYN + j0 + q * 4);
    }
    __syncthreads();
    #pragma unroll 2
    for (int c = 0; c < 40; ++c) {
      float av[2][4], bw[2][4];
      *(float4*)av[0] = *(const float4*)&sA[c][i16 * 4];
      *(float4*)av[1] = *(const float4*)&sA[c][64 + i16 * 4];
      *(float4*)bw[0] = *(const float4*)&sB[c][j16 * 4];
      *(float4*)bw[1] = *(const float4*)&sB[c][64 + j16 * 4];
      #pragma unroll
      for (int p = 0; p < 2; ++p)
        #pragma unroll
        for (int jj = 0; jj < 4; ++jj)
          #pragma unroll
          for (int q = 0; q < 2; ++q)
            #pragma unroll
            for (int i = 0; i < 4; ++i)
              acc[p][jj][q][i] = fmaf(av[q][i], bw[p][jj], acc[p][jj][q][i]);
    }
  }

  float4 xa[2];
  xa[0] = *(const float4*)(x2n + b * TXN + x0 + i16 * 4);
  xa[1] = *(const float4*)(x2n + b * TXN + x0 + 64 + i16 * 4);
  int xb0 = x0 + i16 * 4;
  int xb1 = x0 + 64 + i16 * 4;

  #pragma unroll
  for (int p = 0; p < 2; ++p)
    #pragma unroll
    for (int jj = 0; jj < 4; ++jj) {
      int j = j0 + p * 64 + j16 * 4 + jj;
      if (j >= ml) continue;
      float zz = z2n[b * TYN + j];
      float* row = valT + ((size_t)b * TYN + j) * TXN;
      float4 o;
      o.x = (xb0 + 0 < xl) ? ((xa[0].x + zz) + 2.f * acc[p][jj][0][0]) : 0.f;
      o.y = (xb0 + 1 < xl) ? ((xa[0].y + zz) + 2.f * acc[p][jj][0][1]) : 0.f;
      o.z = (xb0 + 2 < xl) ? ((xa[0].z + zz) + 2.f * acc[p][jj][0][2]) : 0.f;
      o.w = (xb0 + 3 < xl) ? ((xa[0].w + zz) + 2.f * acc[p][jj][0][3]) : 0.f;
      *(float4*)(row + xb0) = o;
      o.x = (xb1 + 0 < xl) ? ((xa[1].x + zz) + 2.f * acc[p][jj][1][0]) : 0.f;
      o.y = (xb1 + 1 < xl) ? ((xa[1].y + zz) + 2.f * acc[p][jj][1][1]) : 0.f;
      o.z = (xb1 + 2 < xl) ? ((xa[1].z + zz) + 2.f * acc[p][jj][1][2]) : 0.f;
      o.w = (xb1 + 3 < xl) ? ((xa[1].w + zz) + 2.f * acc[p][jj][1][3]) : 0.f;
      *(float4*)(row + xb1) = o;
    }
}

// ---------------- K3: Viterbi forward DP (1 wave, LDS ring staging) ----------------
// Lane owns x = 16*lane .. 16*lane+15. LDS ring NR=12 rows filled via
// global_load_lds (un-sinkable async DMA, ordered by explicit vmcnt asm).
// Source pre-swizzle: call q loads global floats 16*lane+4q.. -> LDS quarter q at
// float 256q+4*lane => conflict-free ds_read_b128, val[i] <-> x = 16*lane+i.
// vmcnt(36) at step j guarantees rows <= j+2 resident (4 loads/step, in-order;
// the 16 u16 stores per block also count toward vmcnt — accounting still safe).
// vbuf 4-slot rotation: compute row j from vbuf[j&3]; ds_read row j+2 issued
// AFTER compute so lgkmcnt waits only cover step-old reads.
#define NR 12
__global__ __launch_bounds__(64) void k3_dp(
    const float* __restrict__ valT, const int* __restrict__ mlen,
    u32* __restrict__ staysW) {
  __shared__ float lds[NR * 1024];
  const int b = blockIdx.x;
  const int ml = mlen[b];
  const int lane = threadIdx.x;
  const float* vb = valT + ((size_t)b << 22);

  // prologue: issue rows 0..NR-2 into ring
  for (int r = 0; r < NR - 1; ++r) {
    const float* gp = vb + ((size_t)r << 10) + (lane << 4);
    float* lp = &lds[r << 10];
    GLLDS(gp,      lp);
    GLLDS(gp + 4,  lp + 256);
    GLLDS(gp + 8,  lp + 512);
    GLLDS(gp + 12, lp + 768);
  }

  float v[16];
  #pragma unroll
  for (int i = 0; i < 16; ++i) v[i] = NEGV;
  if (lane == 0) v[0] = 0.f;

  asm volatile("s_waitcnt vmcnt(36)" ::: "memory");  // rows 0,1 resident
  float4 vbuf[4][4];
  #pragma unroll
  for (int q = 0; q < 4; ++q) {
    vbuf[0][q] = *(const float4*)&lds[(0 << 10) + (q << 8) + (lane << 2)];
    vbuf[1][q] = *(const float4*)&lds[(1 << 10) + (q << 8) + (lane << 2)];
  }

  int wSlot = NR - 1;   // LDS slot for the row issued at step j (= row j+NR-1)
  int rSlot = 2;        // LDS slot for ds_read of row j+2
  int gRow  = NR - 1;   // source row for the GLL at step j (clamped at TYN-1)

  u16* sw16 = (u16*)staysW + (((size_t)(b * TXN + (lane << 4))) << 8);

  const int jpad = (ml + 15) & ~15;
  for (int j0 = 0; j0 < jpad; j0 += 16) {
    u32 bh[16];
    #pragma unroll
    for (int i = 0; i < 16; ++i) bh[i] = 0;

    #pragma unroll
    for (int jj = 0; jj < 16; ++jj) {
      const int j = j0 + jj;

      // 1. issue ring load for row gRow (== j+NR-1 until clamp) into wSlot
      {
        const float* gp = vb + ((size_t)gRow << 10) + (lane << 4);
        float* lp = &lds[wSlot << 10];
        GLLDS(gp,      lp);
        GLLDS(gp + 4,  lp + 256);
        GLLDS(gp + 8,  lp + 512);
        GLLDS(gp + 12, lp + 768);
        wSlot = (wSlot == NR - 1) ? 0 : wSlot + 1;
        gRow += (gRow < TYN - 1) ? 1 : 0;
      }

      // 2. ring guarantee: rows <= j+2 resident in LDS
      asm volatile("s_waitcnt vmcnt(36)" ::: "memory");

      // 3. compute step j from vbuf[j&3] (jj&3 static under unroll)
      {
        float e = __shfl_up(v[15], 1);
        if (lane == 0) e = NEGV;

        float val[16];
        #pragma unroll
        for (int q = 0; q < 4; ++q) {
          val[4 * q + 0] = vbuf[jj & 3][q].x;
          val[4 * q + 1] = vbuf[jj & 3][q].y;
          val[4 * q + 2] = vbuf[jj & 3][q].z;
          val[4 * q + 3] = vbuf[jj & 3][q].w;
        }

        #pragma unroll
        for (int i = 15; i >= 1; --i) {
          bool s = v[i] >= v[i - 1];
          v[i] = fmaxf(v[i], v[i - 1]) + val[i];
          bh[i] |= ((u32)s) << jj;
        }
        {
          bool s = v[0] >= e;
          v[0] = fmaxf(v[0], e) + val[0];
          bh[0] |= ((u32)s) << jj;
        }

        // force one-above-diagonal cell to exact NEG ((jj+1)&15 static)
        {
          int lt = (j + 1) >> 4;
          if (lane == lt) v[(jj + 1) & 15] = NEGV;
        }
      }

      // 4. ds_read row j+2 into vbuf[(j+2)&3] (consumed 2 steps later)
      #pragma unroll
      for (int q = 0; q < 4; ++q)
        vbuf[(jj + 2) & 3][q] = *(const float4*)&lds[(rSlot << 10) + (q << 8) + (lane << 2)];
      rSlot = (rSlot == NR - 1) ? 0 : rSlot + 1;
    }

    const int h = j0 >> 4;
    #pragma unroll
    for (int i = 0; i < 16; ++i) sw16[(i << 8) + h] = (u16)bh[i];
  }
}

// ---------------- K4: backtrack (run-skipping on transposed bits) ----------------
__global__ __launch_bounds__(256) void k4_backtrack(
    const u32* __restrict__ staysW, const int* __restrict__ xlen, const int* __restrict__ mlen,
    int* __restrict__ idxArr, float* __restrict__ out_logw) {
  int b = blockIdx.x;
  int xl = xlen[b], ml = mlen[b];
  int t = threadIdx.x;
  __shared__ u32 win[64][128];
  __shared__ u16 lidx[TYN];
  __shared__ u16 ldur[TXN];
  __shared__ int st[3];

  for (int i = t; i < TXN; i += 256) ldur[i] = 0;
  if (t == 0) { st[0] = xl - 1; st[1] = ml - 1; st[2] = ml - 1; }
  __syncthreads();

  int wb = (xl - 1) >> 6;
  for (int i = t; i < 64 * 128; i += 256) {
    int r = i >> 7, wq = i & 127;
    win[r][wq] = staysW[((size_t)(b * TXN + (wb << 6) + r) << 7) + wq];
  }
  __syncthreads();

  while (true) {
    if (t == 0) {
      int idx = st[0], j = st[1], end = st[2];
      while (j >= 0 && (idx >> 6) == wb) {
        u32 w = win[idx & 63][j >> 5];
        int p = j & 31;
        u32 below = w << (31 - p);
        u32 inv = ~below;
        int ones = (inv != 0u) ? __builtin_clz(inv) : 32;
        if (ones > p) {
          j -= p + 1;                      // whole rest of word is "stay"
        } else {
          int jz = j - ones;               // dir==0 at step jz -> move down
          for (int q = jz; q <= end; ++q) lidx[q] = (u16)idx;
          ldur[idx] = (u16)(end - jz + 1);
          end = jz - 1;
          j = jz - 1;
          idx -= 1;
        }
      }
      if (j < 0) {
        for (int q = 0; q <= end; ++q) lidx[q] = (u16)idx;
        if (idx >= 0 && end >= 0) ldur[idx] = (u16)(end + 1);
      }
      st[0] = idx; st[1] = j; st[2] = end;
    }
    __syncthreads();
    if (st[1] < 0) break;
    wb = st[0] >> 6;
    for (int i = t; i < 64 * 128; i += 256) {
      int r = i >> 7, wq = i & 127;
      win[r][wq] = staysW[((size_t)(b * TXN + (wb << 6) + r) << 7) + wq];
    }
    __syncthreads();
  }

  for (int q = t; q < TYN; q += 256) idxArr[b * TYN + q] = (q < ml) ? (int)lidx[q] : -1;
  for (int x = t; x < TXN; x += 256)
    out_logw[b * TXN + x] = (x < xl) ? logf(1e-8f + (float)ldur[x]) : 0.f;
}

// ---------------- K5a: write attn (full pass, 0/1) ----------------
__global__ __launch_bounds__(256) void k5_attn(
    const int* __restrict__ idxArr, float* __restrict__ attn) {
  int b = blockIdx.z;
  int x = blockIdx.y;
  int j = blockIdx.x * 1024 + threadIdx.x * 4;
  int4 iv = *(const int4*)(idxArr + b * TYN + j);
  float4 o;
  o.x = (iv.x == x) ? 1.f : 0.f;
  o.y = (iv.y == x) ? 1.f : 0.f;
  o.z = (iv.z == x) ? 1.f : 0.f;
  o.w = (iv.w == x) ? 1.f : 0.f;
  *(float4*)(attn + ((size_t)(b * TXN + x)) * TYN + j) = o;
}

// ---------------- K5b: z_m gather ----------------
__global__ __launch_bounds__(256) void k5_zm(
    const int* __restrict__ idxArr, const float* __restrict__ xres, float* __restrict__ zm) {
  int bid = blockIdx.x; int b = bid >> 8; int c = bid & 255;
  const float* row = xres + (size_t)(b * DRES + c) * TXN;
  float* orow = zm + (size_t)(b * DRES + c) * TYN;
  const int* ia = idxArr + b * TYN;
  for (int j = threadIdx.x; j < TYN; j += 256) {
    int idx = ia[j];
    orow[j] = (idx >= 0) ? row[idx] : 0.f;
  }
}

// ---------------- K5c: mel_proj gather + loss partials ----------------
__global__ __launch_bounds__(256) void k5_mproj(
    const int* __restrict__ idxArr, const float* __restrict__ xm,
    const float* __restrict__ noise, const float* __restrict__ mel,
    float* __restrict__ mproj, float* __restrict__ partials) {
  int bid = blockIdx.x; int b = bid / CMEL; int c = bid % CMEL;
  const float* row  = xm    + (size_t)(b * CMEL + c) * TXN;
  const float* nrow = noise + (size_t)(b * CMEL + c) * TYN;
  const float* mrow = mel   + (size_t)(b * CMEL + c) * TYN;
  float* orow = mproj + (size_t)(b * CMEL + c) * TYN;
  const int* ia = idxArr + b * TYN;
  float acc = 0.f;
  for (int j = threadIdx.x; j < TYN; j += 256) {
    int idx = ia[j];
    float g = (idx >= 0) ? row[idx] : 0.f;
    float mp = g + nrow[j];
    orow[j] = mp;
    float d = mp - mrow[j];
    acc += (idx >= 0) ? fabsf(d) : 0.f;
  }
  #pragma unroll
  for (int o = 32; o; o >>= 1) acc += __shfl_down(acc, o);
  __shared__ float ws4[4];
  if ((threadIdx.x & 63) == 0) ws4[threadIdx.x >> 6] = acc;
  __syncthreads();
  if (threadIdx.x == 0) partials[bid] = (ws4[0] + ws4[1]) + (ws4[2] + ws4[3]);
}

// ---------------- K6: final loss reduce ----------------
__global__ __launch_bounds__(256) void k6_loss(
    const float* __restrict__ partials, float* __restrict__ out_loss) {
  float acc = 0.f;
  for (int i = threadIdx.x; i < BB * CMEL; i += 256) acc += partials[i];
  #pragma unroll
  for (int o = 32; o; o >>= 1) acc += __shfl_down(acc, o);
  __shared__ float ws4[4];
  if ((threadIdx.x & 63) == 0) ws4[threadIdx.x >> 6] = acc;
  __syncthreads();
  if (threadIdx.x == 0)
    out_loss[0] = ((ws4[0] + ws4[1]) + (ws4[2] + ws4[3])) * (1.0f / ((float)BB * CMEL * TYN));
}

extern "C" void kernel_launch(void* const* d_in, const int* in_sizes, int n_in,
                              void* d_out, int out_size, void* d_ws, size_t ws_size,
                              hipStream_t stream) {
  const float* xm    = (const float*)d_in[0];
  const float* xres  = (const float*)d_in[1];
  const float* mel   = (const float*)d_in[2];
  const int*   xlen  = (const int*)d_in[3];
  const int*   mlen  = (const int*)d_in[4];
  const float* noise = (const float*)d_in[5];

  float* out = (float*)d_out;
  float* out_zm    = out + OFF_ZM;
  float* out_zmask = out + OFF_ZMASK;
  float* out_attn  = out + OFF_ATTN;
  float* out_logw  = out + OFF_LOGW;
  float* out_loss  = out + OFF_LOSS;
  float* out_mproj = out + OFF_MPROJ;

  char* ws = (char*)d_ws;
  float* x2n      = (float*)(ws + WS_X2);
  float* z2n      = (float*)(ws + WS_Z2);
  int*   idxArr   = (int*)(ws + WS_IDX);
  float* partials = (float*)(ws + WS_PART);

  // scratch aliases inside output regions (consumed before region is rewritten)
  float* valT   = out_attn;        // [b][j][x], read by K3, overwritten by K5a
  u32*   staysW = (u32*)out_zm;    // 8 MB of z_m region, read by K4, overwritten by K5b

  hipLaunchKernelGGL(k1_prep, dim3(BB, 5), dim3(1024), 0, stream, xm, mel, mlen, x2n, z2n, out_zmask);
  hipLaunchKernelGGL(k2_corr, dim3(8, 32, BB), dim3(256), 0, stream, xm, mel, x2n, z2n, xlen, mlen, valT);
  hipLaunchKernelGGL(k3_dp, dim3(BB), dim3(64), 0, stream, valT, mlen, staysW);
  hipLaunchKernelGGL(k4_backtrack, dim3(BB), dim3(256), 0, stream, staysW, xlen, mlen, idxArr, out_logw);
  hipLaunchKernelGGL(k5_attn, dim3(4, TXN, BB), dim3(256), 0, stream, idxArr, out_attn);
  hipLaunchKernelGGL(k5_zm, dim3(BB * DRES), dim3(256), 0, stream, idxArr, xres, out_zm);
  hipLaunchKernelGGL(k5_mproj, dim3(BB * CMEL), dim3(256), 0, stream, idxArr, xm, noise, mel, out_mproj, partials);
  hipLaunchKernelGGL(k6_loss, dim3(1), dim3(256), 0, stream, partials, out_loss);
}